// Round 3
// baseline (1291.083 us; speedup 1.0000x reference)
//
#include <hip/hip_runtime.h>
#include <math.h>

#define B_ 4
#define CIN_ 32
#define HID_ 32
#define T_ 31
#define H_ 96
#define W_ 96
#define SP_ (H_*W_)

typedef _Float16 half8 __attribute__((ext_vector_type(8)));
typedef float f32x4 __attribute__((ext_vector_type(4)));
typedef float f32x16 __attribute__((ext_vector_type(16)));

// ---------------------------------------------------------------------------
// Kernel 0: weights fp32 -> fp16 MFMA A-fragment layout (all 64 oc).
// wr[((tap*4 + a)*64 + lane)*8 + i] : A[m][k] for mfma_f32_16x16x32_f16
//   oc = a*16 + (lane&15), cin = ((lane>>4)&3)*8 + i
// ---------------------------------------------------------------------------
__global__ __launch_bounds__(256) void prep_w_kernel(
    const float* __restrict__ w, _Float16* __restrict__ wr) {
  int idx = blockIdx.x * 256 + threadIdx.x;
  if (idx >= 55296) return;
  int i = idx & 7;
  int lane = (idx >> 3) & 63;
  int a = (idx >> 9) & 3;
  int tap = idx >> 11;            // 0..26
  int oc = a * 16 + (lane & 15);
  int cin = ((lane >> 4) & 3) * 8 + i;
  wr[idx] = (_Float16)(w[(oc * CIN_ + cin) * 27 + tap]);
}

// ---------------------------------------------------------------------------
// Kernel 1: fused Conv3d (fp16 MFMA) + gating + time recurrence.
// Block = 2 waves (128 thr), tile 16x4 px; wave w owns rows 2w,2w+1.
// Wave computes 64 oc x 32 px: acc[a=ocfrag 0..3][r=row 0..1].
// A-frags streamed from global (L2-resident, 110 KB); B from LDS ring.
// Ring: 4 slots x [6 rows x 18 cols][pitch 40 f16] -> stage(t+2) || compute(t).
// B-row reuse: per (kd,kw) read rows 2w..2w+3 once, serve kh=0..2.
// ---------------------------------------------------------------------------
#define PITCH 40
#define SLICE_HF (108 * PITCH)   // 4320 f16 = 8640 B per slice

__global__ __launch_bounds__(128) void conv_rec_mfma(
    const float* __restrict__ in, const _Float16* __restrict__ wr,
    const float* __restrict__ bias, float* __restrict__ out) {
  __shared__ _Float16 in_s[4 * SLICE_HF];   // 34.5 KB

  const int tid = threadIdx.x;
  const int tile = blockIdx.x;   // 0..143
  const int b = blockIdx.y;      // 0..3
  const int x0 = (tile % 6) * 16;
  const int y0 = (tile / 6) * 4;
  const int lane = tid & 63;
  const int wv = tid >> 6;       // 0..1
  const int px = lane & 15;
  const int kq = lane >> 4;      // 0..3

  auto stage = [&](int ts, int slot) {
    _Float16* dst = in_s + slot * SLICE_HF;
    for (int e = tid; e < 3456; e += 128) {   // 27 iters
      int xx = e % 18;
      int rr = e / 18;
      int yy = rr % 6;
      int cin = rr / 6;
      int gy = y0 - 1 + yy, gx = x0 - 1 + xx;
      float v = 0.f;
      if ((unsigned)ts < (unsigned)T_ && (unsigned)gy < (unsigned)H_ &&
          (unsigned)gx < (unsigned)W_)
        v = in[((b * CIN_ + cin) * T_ + ts) * SP_ + gy * W_ + gx];
      dst[(yy * 18 + xx) * PITCH + cin] = (_Float16)v;
    }
  };

  // bias fragments (acc init): bias[a*16 + kq*4 + j]
  f32x4 bfr[4];
#pragma unroll
  for (int a = 0; a < 4; ++a)
#pragma unroll
    for (int j = 0; j < 4; ++j) bfr[a][j] = bias[a * 16 + kq * 4 + j];

  const _Float16* wbase = wr + lane * 8;   // + (tap*4+a)*512

  stage(-1, 3);
  stage(0, 0);
  stage(1, 1);
  __syncthreads();

  float h[2][2][4];
#pragma unroll
  for (int a = 0; a < 2; ++a)
#pragma unroll
    for (int r = 0; r < 2; ++r)
#pragma unroll
      for (int j = 0; j < 4; ++j) h[a][r][j] = 0.f;

  for (int t = 0; t < T_; ++t) {
    stage(t + 2, (t + 2) & 3);   // zeros when t+2 >= 31; overlaps compute(t)

    f32x4 acc[4][2];
#pragma unroll
    for (int a = 0; a < 4; ++a) { acc[a][0] = bfr[a]; acc[a][1] = bfr[a]; }

#pragma unroll
    for (int kd = 0; kd < 3; ++kd) {
      const _Float16* sb = in_s + ((t + 3 + kd) & 3) * SLICE_HF;  // slice t-1+kd
#pragma unroll
      for (int kw = 0; kw < 3; ++kw) {
        half8 brr[4];
#pragma unroll
        for (int rr = 0; rr < 4; ++rr)
          brr[rr] = *(const half8*)(sb + ((2 * wv + rr) * 18 + px + kw) * PITCH + kq * 8);
#pragma unroll
        for (int kh = 0; kh < 3; ++kh) {
          const int tap = kd * 9 + kh * 3 + kw;
#pragma unroll
          for (int a = 0; a < 4; ++a) {
            half8 af = *(const half8*)(wbase + (tap * 4 + a) * 512);
            acc[a][0] = __builtin_amdgcn_mfma_f32_16x16x32_f16(af, brr[kh], acc[a][0], 0, 0, 0);
            acc[a][1] = __builtin_amdgcn_mfma_f32_16x16x32_f16(af, brr[kh + 1], acc[a][1], 0, 0, 0);
          }
        }
      }
    }

    // gating + recurrence + store; oc = a*16 + kq*4 + j (Z: a=0,1; F: a+2)
#pragma unroll
    for (int a = 0; a < 2; ++a)
#pragma unroll
      for (int r = 0; r < 2; ++r)
#pragma unroll
        for (int j = 0; j < 4; ++j) {
          float gz = acc[a][r][j];
          float gf = acc[a + 2][r][j];
          gz = fminf(fmaxf(gz, -20.f), 20.f);
          float ez = __expf(2.f * gz);
          float zz = (ez - 1.f) / (ez + 1.f);            // tanh
          float ff = 1.f / (1.f + __expf(-gf));          // sigmoid
          h[a][r][j] = ff * h[a][r][j] + (1.f - ff) * zz;
          int c = a * 16 + kq * 4 + j;
          out[((b * HID_ + c) * T_ + t) * SP_ + (y0 + 2 * wv + r) * W_ + x0 + px] =
              h[a][r][j];
        }
    __syncthreads();
  }
}

// ---------------------------------------------------------------------------
// Kernel 2: per-pixel channel attention via 32x32x16 MFMA, in-place on d_out.
// Block = 4 waves (256 thr), 8 pixels (x0..x0+7, one row y). Wave -> 2 px.
// qh_s[px][c*40+t] (t=31 zeroed), qt_s[px][t*40+c] (transposed copy).
// QK^T: same half8 is both A and B (S = qh . qh^T). Softmax over c = reg axis.
// attn -> at_s[wave] f16; PV: A=attn frags, B=qt frags. Result into qt_s.
// ---------------------------------------------------------------------------
#define APIT 40

__global__ __launch_bounds__(256) void attn_mfma(
    float* __restrict__ out, const float* __restrict__ gamma) {
  __shared__ _Float16 qh_s[8][32 * APIT];   // 20480 B
  __shared__ _Float16 qt_s[8][32 * APIT];   // 20480 B
  __shared__ _Float16 at_s[4][32 * APIT];   // 10240 B

  const int tid = threadIdx.x;
  const int x0 = blockIdx.x * 8;
  const int y = blockIdx.y;
  const int b = blockIdx.z;
  const int lane = tid & 63;
  const int wv = tid >> 6;
  const float gm = gamma[0];

  // stage h (coalesced global reads), both layouts
  for (int e = tid; e < 7936; e += 256) {   // 8 px * 32 c * 31 t
    int xi = e & 7;
    int q = e >> 3;
    int t = q % 31;
    int c = q / 31;
    float v = out[((b * HID_ + c) * T_ + t) * SP_ + y * W_ + x0 + xi];
    _Float16 hv = (_Float16)v;
    qh_s[xi][c * APIT + t] = hv;
    qt_s[xi][t * APIT + c] = hv;
  }
  {  // zero-pad t=31 column of qh_s
    int xi = tid & 7;
    int c = tid >> 3;
    if (c < 32) qh_s[xi][c * APIT + 31] = (_Float16)0.f;
  }
  __syncthreads();

  const int cd = lane & 31;      // c-or-d-or-t index (col role)
  const int hi = lane >> 5;

#pragma unroll
  for (int pp = 0; pp < 2; ++pp) {
    const int px = wv * 2 + pp;

    // QK^T: S[c][d] = sum_t qh[c][t] qh[d][t]
    half8 q0 = *(const half8*)&qh_s[px][cd * APIT + hi * 8];
    half8 q1 = *(const half8*)&qh_s[px][cd * APIT + hi * 8 + 16];
    f32x16 S = {};
    S = __builtin_amdgcn_mfma_f32_32x32x16_f16(q0, q0, S, 0, 0, 0);
    S = __builtin_amdgcn_mfma_f32_32x32x16_f16(q1, q1, S, 0, 0, 0);

    // softmax over c (rows live in regs + lane^32), then * 1/sqrt(32)
    float mx = S[0];
#pragma unroll
    for (int r = 1; r < 16; ++r) mx = fmaxf(mx, S[r]);
    mx = fmaxf(mx, __shfl_xor(mx, 32));
    float sm = 0.f;
    float ev[16];
#pragma unroll
    for (int r = 0; r < 16; ++r) { ev[r] = __expf(S[r] - mx); sm += ev[r]; }
    sm += __shfl_xor(sm, 32);
    const float sc = 0.17677669529663688f / sm;

    // write attn[c][d] to at_s (c from reg decode, d = cd)
#pragma unroll
    for (int r = 0; r < 16; ++r) {
      int c = (r & 3) + 8 * (r >> 2) + 4 * hi;
      at_s[wv][c * APIT + cd] = (_Float16)(ev[r] * sc);
    }

    // PV: P[c][t] = sum_d attn[c][d] qh[d][t]
    half8 a0 = *(const half8*)&at_s[wv][cd * APIT + hi * 8];
    half8 a1 = *(const half8*)&at_s[wv][cd * APIT + hi * 8 + 16];
    half8 b0 = *(const half8*)&qt_s[px][cd * APIT + hi * 8];
    half8 b1 = *(const half8*)&qt_s[px][cd * APIT + hi * 8 + 16];
    f32x16 P = {};
    P = __builtin_amdgcn_mfma_f32_32x32x16_f16(a0, b0, P, 0, 0, 0);
    P = __builtin_amdgcn_mfma_f32_32x32x16_f16(a1, b1, P, 0, 0, 0);

    // result (lane holds t = cd, c in regs) -> qt_s[px][t*APIT + c]
#pragma unroll
    for (int r = 0; r < 16; ++r) {
      int c = (r & 3) + 8 * (r >> 2) + 4 * hi;
      qt_s[px][cd * APIT + c] = (_Float16)P[r];
    }
  }
  __syncthreads();

  // store: out = gamma * ah + h   (coalesced)
  for (int e = tid; e < 7936; e += 256) {
    int xi = e & 7;
    int q = e >> 3;
    int t = q % 31;
    int c = q / 31;
    float ah = (float)qt_s[xi][t * APIT + c];
    float hv = (float)qh_s[xi][c * APIT + t];
    out[((b * HID_ + c) * T_ + t) * SP_ + y * W_ + x0 + xi] = gm * ah + hv;
  }
}

// ---------------------------------------------------------------------------
extern "C" void kernel_launch(void* const* d_in, const int* in_sizes, int n_in,
                              void* d_out, int out_size, void* d_ws,
                              size_t ws_size, hipStream_t stream) {
  const float* in    = (const float*)d_in[0];  // [4,32,31,96,96]
  const float* w     = (const float*)d_in[1];  // [64,32,3,3,3]
  const float* bias  = (const float*)d_in[2];  // [64]
  const float* gamma = (const float*)d_in[3];  // [1]
  float* out = (float*)d_out;                  // [4,32,31,96,96]
  _Float16* wr = (_Float16*)d_ws;              // 110 KB fp16 fragments

  prep_w_kernel<<<216, 256, 0, stream>>>(w, wr);
  conv_rec_mfma<<<dim3(144, 4), 128, 0, stream>>>(in, wr, bias, out);
  attn_mfma<<<dim3(12, 96, 4), 256, 0, stream>>>(out, gamma);
}

// Round 5
// 494.254 us; speedup vs baseline: 2.6122x; 2.6122x over previous
//
#include <hip/hip_runtime.h>
#include <math.h>

#define B_ 4
#define CIN_ 32
#define HID_ 32
#define T_ 31
#define H_ 96
#define W_ 96
#define SP_ (H_*W_)

typedef _Float16 half8 __attribute__((ext_vector_type(8)));
typedef float f32x4 __attribute__((ext_vector_type(4)));
typedef float f32x16 __attribute__((ext_vector_type(16)));

// ---------------------------------------------------------------------------
// Kernel 0: weights fp32 -> fp16 MFMA A-fragments.
// wr[((cg*27 + tap)*2 + g)*512 + lane*8 + i]
//   oc = g*32 + cg*16 + (lane&15), cin = ((lane>>4)&3)*8 + i
// (g=0 -> Z channel, g=1 -> its F partner; cg = channel group 0..1)
// ---------------------------------------------------------------------------
__global__ __launch_bounds__(256) void prep_w_kernel(
    const float* __restrict__ w, _Float16* __restrict__ wr) {
  int idx = blockIdx.x * 256 + threadIdx.x;
  if (idx >= 55296) return;
  int i = idx & 7;
  int lane = (idx >> 3) & 63;
  int g = (idx >> 9) & 1;
  int rest = idx >> 10;            // cg*27 + tap
  int tap = rest % 27;
  int cg = rest / 27;
  int oc = g * 32 + cg * 16 + (lane & 15);
  int cin = ((lane >> 4) & 3) * 8 + i;
  wr[idx] = (_Float16)(w[(oc * CIN_ + cin) * 27 + tap]);
}

// ---------------------------------------------------------------------------
// Kernel 1: fused Conv3d (fp16 MFMA) + gating + time recurrence.
// Grid 48x4 (16x12 px tiles), block 256 thr = 4 waves.
// Wave (cg = wv&1, rg = wv>>1): channels cg*16..+15 (Z AND F partners, so
// gating is in-lane), rows rg*6..rg*6+5. Weights for the wave's 32 oc are
// held in 216 VGPRs for the whole kernel -> zero per-t A-operand traffic.
// Input ring: 4 slots x [14 rows x 18 cols][pitch 40 f16] = 80.6 KB LDS;
// slice t+2 is loaded to regs at top of t (latency under MFMA), written to
// its ring slot after compute, one barrier per t.
// Ring safety: compute(t) reads slots (t-1..t+1)&3, write targets (t+2)&3 —
// disjoint; barrier at end of t orders the write before compute(t+1) reads.
// ---------------------------------------------------------------------------
#define PITCH 40
#define SROWS 14
#define SCOLS 18
#define SLICE_HF (SROWS * SCOLS * PITCH)   // 10080 f16
#define NSTG (SROWS * SCOLS * CIN_)        // 8064 elems per slice

__global__ __launch_bounds__(256, 1) void conv_rec_mfma(
    const float* __restrict__ in, const _Float16* __restrict__ wr,
    const float* __restrict__ bias, float* __restrict__ out) {
  __shared__ _Float16 in_s[4 * SLICE_HF];   // 80640 B

  const int tid = threadIdx.x;
  const int tile = blockIdx.x;   // 0..47
  const int b = blockIdx.y;      // 0..3
  const int x0 = (tile % 6) * 16;
  const int y0 = (tile / 6) * 12;
  const int lane = tid & 63;
  const int wv = tid >> 6;
  const int cg = wv & 1;         // channel group
  const int rg = wv >> 1;        // row group
  const int px = lane & 15;
  const int kq = lane >> 4;      // k-quarter (cin/8)

  // --- per-wave weights into registers: 27 taps x {Z,F} = 216 VGPR ---
  half8 wz[27], wf[27];
  {
    const _Float16* wp = wr + (size_t)(cg * 54) * 512 + lane * 8;
#pragma unroll
    for (int tap = 0; tap < 27; ++tap) {
      wz[tap] = *(const half8*)(wp + (tap * 2 + 0) * 512);
      wf[tap] = *(const half8*)(wp + (tap * 2 + 1) * 512);
    }
  }

  // bias fragments: c = cg*16 + kq*4 + j
  f32x4 bz4, bf4;
#pragma unroll
  for (int j = 0; j < 4; ++j) {
    bz4[j] = bias[cg * 16 + kq * 4 + j];
    bf4[j] = bias[32 + cg * 16 + kq * 4 + j];
  }

  // --- staging helper: slice ts -> slot ts&3 (prologue only) ---
  auto stage_direct = [&](int ts) {
    _Float16* dst = in_s + (ts & 3) * SLICE_HF;
#pragma unroll 4
    for (int k = 0; k < 32; ++k) {
      int e = tid + k * 256;
      if (e < NSTG) {
        int xx = e % SCOLS;
        int r = e / SCOLS;
        int yy = r % SROWS;
        int cin = r / SROWS;
        int gy = y0 - 1 + yy, gx = x0 - 1 + xx;
        float v = 0.f;
        if ((unsigned)ts < (unsigned)T_ && (unsigned)gy < (unsigned)H_ &&
            (unsigned)gx < (unsigned)W_)
          v = in[((b * CIN_ + cin) * T_ + ts) * SP_ + gy * W_ + gx];
        dst[(yy * SCOLS + xx) * PITCH + cin] = (_Float16)v;
      }
    }
  };

  // prologue: slot 3 = slice -1 = zeros (single writer pass, no race);
  // then slices 0,1 into slots 0,1.
  {
    _Float16* dst = in_s + 3 * SLICE_HF;
    for (int e = tid; e < SLICE_HF; e += 256) dst[e] = (_Float16)0.f;
  }
  stage_direct(0);
  stage_direct(1);
  __syncthreads();

  float h[6][4];
#pragma unroll
  for (int r = 0; r < 6; ++r)
#pragma unroll
    for (int j = 0; j < 4; ++j) h[r][j] = 0.f;

  for (int t = 0; t < T_; ++t) {
    // ---- issue stage loads for slice t+2 (latency hides under MFMA) ----
    const int ts = t + 2;
    float sv[32];
#pragma unroll
    for (int k = 0; k < 32; ++k) {
      int e = tid + k * 256;
      sv[k] = 0.f;
      if (e < NSTG && ts < T_) {
        int xx = e % SCOLS;
        int r = e / SCOLS;
        int yy = r % SROWS;
        int cin = r / SROWS;
        int gy = y0 - 1 + yy, gx = x0 - 1 + xx;
        if ((unsigned)gy < (unsigned)H_ && (unsigned)gx < (unsigned)W_)
          sv[k] = in[((b * CIN_ + cin) * T_ + ts) * SP_ + gy * W_ + gx];
      }
    }

    // ---- compute: 27 taps, 6 rows, Z+F ----
    f32x4 acc[2][6];
#pragma unroll
    for (int r = 0; r < 6; ++r) { acc[0][r] = bz4; acc[1][r] = bf4; }

#pragma unroll
    for (int kd = 0; kd < 3; ++kd) {
      const _Float16* sb = in_s + ((t + 3 + kd) & 3) * SLICE_HF;  // slice t-1+kd
#pragma unroll
      for (int kw = 0; kw < 3; ++kw) {
        half8 brow[8];
#pragma unroll
        for (int rr = 0; rr < 8; ++rr)
          brow[rr] = *(const half8*)(sb + ((rg * 6 + rr) * SCOLS + px + kw) * PITCH + kq * 8);
#pragma unroll
        for (int kh = 0; kh < 3; ++kh) {
          const int tap = kd * 9 + kh * 3 + kw;
#pragma unroll
          for (int r = 0; r < 6; ++r) {
            acc[0][r] = __builtin_amdgcn_mfma_f32_16x16x32_f16(wz[tap], brow[r + kh], acc[0][r], 0, 0, 0);
            acc[1][r] = __builtin_amdgcn_mfma_f32_16x16x32_f16(wf[tap], brow[r + kh], acc[1][r], 0, 0, 0);
          }
        }
      }
    }

    // ---- write staged slice to ring slot (t+2)&3 ----
    {
      _Float16* dst = in_s + (ts & 3) * SLICE_HF;
#pragma unroll
      for (int k = 0; k < 32; ++k) {
        int e = tid + k * 256;
        if (e < NSTG) {
          int xx = e % SCOLS;
          int r = e / SCOLS;
          int yy = r % SROWS;
          int cin = r / SROWS;
          dst[(yy * SCOLS + xx) * PITCH + cin] = (_Float16)sv[k];
        }
      }
    }

    // ---- gating + recurrence + store ----
#pragma unroll
    for (int r = 0; r < 6; ++r)
#pragma unroll
      for (int j = 0; j < 4; ++j) {
        float zz = 1.f - 2.f / (1.f + __expf(2.f * acc[0][r][j]));   // tanh
        float ff = 1.f / (1.f + __expf(-acc[1][r][j]));              // sigmoid
        h[r][j] = ff * h[r][j] + (1.f - ff) * zz;
        int c = cg * 16 + kq * 4 + j;
        out[((b * HID_ + c) * T_ + t) * SP_ + (y0 + rg * 6 + r) * W_ + x0 + px] =
            h[r][j];
      }
    __syncthreads();   // stage(t+2) visible before compute(t+1); ring safety
  }
}

// ---------------------------------------------------------------------------
// Kernel 2: per-pixel channel attention via 32x32x16 MFMA, in-place on d_out.
// (unchanged — passed at ~115 us)
// ---------------------------------------------------------------------------
#define APIT 40

__global__ __launch_bounds__(256) void attn_mfma(
    float* __restrict__ out, const float* __restrict__ gamma) {
  __shared__ _Float16 qh_s[8][32 * APIT];   // 20480 B
  __shared__ _Float16 qt_s[8][32 * APIT];   // 20480 B
  __shared__ _Float16 at_s[4][32 * APIT];   // 10240 B

  const int tid = threadIdx.x;
  const int x0 = blockIdx.x * 8;
  const int y = blockIdx.y;
  const int b = blockIdx.z;
  const int lane = tid & 63;
  const int wv = tid >> 6;
  const float gm = gamma[0];

  for (int e = tid; e < 7936; e += 256) {   // 8 px * 32 c * 31 t
    int xi = e & 7;
    int q = e >> 3;
    int t = q % 31;
    int c = q / 31;
    float v = out[((b * HID_ + c) * T_ + t) * SP_ + y * W_ + x0 + xi];
    _Float16 hv = (_Float16)v;
    qh_s[xi][c * APIT + t] = hv;
    qt_s[xi][t * APIT + c] = hv;
  }
  {  // zero-pad t=31 column of qh_s
    int xi = tid & 7;
    int c = tid >> 3;
    if (c < 32) qh_s[xi][c * APIT + 31] = (_Float16)0.f;
  }
  __syncthreads();

  const int cd = lane & 31;
  const int hi = lane >> 5;

#pragma unroll
  for (int pp = 0; pp < 2; ++pp) {
    const int px = wv * 2 + pp;

    // QK^T: S[c][d] = sum_t qh[c][t] qh[d][t]
    half8 q0 = *(const half8*)&qh_s[px][cd * APIT + hi * 8];
    half8 q1 = *(const half8*)&qh_s[px][cd * APIT + hi * 8 + 16];
    f32x16 S = {};
    S = __builtin_amdgcn_mfma_f32_32x32x16_f16(q0, q0, S, 0, 0, 0);
    S = __builtin_amdgcn_mfma_f32_32x32x16_f16(q1, q1, S, 0, 0, 0);

    // softmax over c (rows in regs + lane^32)
    float mx = S[0];
#pragma unroll
    for (int r = 1; r < 16; ++r) mx = fmaxf(mx, S[r]);
    mx = fmaxf(mx, __shfl_xor(mx, 32));
    float sm = 0.f;
    float ev[16];
#pragma unroll
    for (int r = 0; r < 16; ++r) { ev[r] = __expf(S[r] - mx); sm += ev[r]; }
    sm += __shfl_xor(sm, 32);
    const float sc = 0.17677669529663688f / sm;

#pragma unroll
    for (int r = 0; r < 16; ++r) {
      int c = (r & 3) + 8 * (r >> 2) + 4 * hi;
      at_s[wv][c * APIT + cd] = (_Float16)(ev[r] * sc);
    }

    // PV: P[c][t] = sum_d attn[c][d] qh[d][t]
    half8 a0 = *(const half8*)&at_s[wv][cd * APIT + hi * 8];
    half8 a1 = *(const half8*)&at_s[wv][cd * APIT + hi * 8 + 16];
    half8 b0 = *(const half8*)&qt_s[px][cd * APIT + hi * 8];
    half8 b1 = *(const half8*)&qt_s[px][cd * APIT + hi * 8 + 16];
    f32x16 P = {};
    P = __builtin_amdgcn_mfma_f32_32x32x16_f16(a0, b0, P, 0, 0, 0);
    P = __builtin_amdgcn_mfma_f32_32x32x16_f16(a1, b1, P, 0, 0, 0);

#pragma unroll
    for (int r = 0; r < 16; ++r) {
      int c = (r & 3) + 8 * (r >> 2) + 4 * hi;
      qt_s[px][cd * APIT + c] = (_Float16)P[r];
    }
  }
  __syncthreads();

  for (int e = tid; e < 7936; e += 256) {
    int xi = e & 7;
    int q = e >> 3;
    int t = q % 31;
    int c = q / 31;
    float ah = (float)qt_s[xi][t * APIT + c];
    float hv = (float)qh_s[xi][c * APIT + t];
    out[((b * HID_ + c) * T_ + t) * SP_ + y * W_ + x0 + xi] = gm * ah + hv;
  }
}

// ---------------------------------------------------------------------------
extern "C" void kernel_launch(void* const* d_in, const int* in_sizes, int n_in,
                              void* d_out, int out_size, void* d_ws,
                              size_t ws_size, hipStream_t stream) {
  const float* in    = (const float*)d_in[0];  // [4,32,31,96,96]
  const float* w     = (const float*)d_in[1];  // [64,32,3,3,3]
  const float* bias  = (const float*)d_in[2];  // [64]
  const float* gamma = (const float*)d_in[3];  // [1]
  float* out = (float*)d_out;                  // [4,32,31,96,96]
  _Float16* wr = (_Float16*)d_ws;              // 110 KB fp16 fragments

  prep_w_kernel<<<216, 256, 0, stream>>>(w, wr);
  conv_rec_mfma<<<dim3(48, 4), 256, 0, stream>>>(in, wr, bias, out);
  attn_mfma<<<dim3(12, 96, 4), 256, 0, stream>>>(out, gamma);
}

// Round 6
// 383.136 us; speedup vs baseline: 3.3698x; 1.2900x over previous
//
#include <hip/hip_runtime.h>
#include <math.h>

#define B_ 4
#define CIN_ 32
#define HID_ 32
#define T_ 31
#define H_ 96
#define W_ 96
#define SP_ (H_*W_)

typedef _Float16 half8 __attribute__((ext_vector_type(8)));
typedef float f32x4 __attribute__((ext_vector_type(4)));
typedef float f32x16 __attribute__((ext_vector_type(16)));

// ---------------------------------------------------------------------------
// Kernel 0: weights fp32 -> fp16 gate-interleaved MFMA A-fragments.
// wr[((ocg*27 + tap)*64 + lane)*8 + i]
//   m = lane&15: gate = m&1, ch = ocg*8 + (m>>1); global oc = gate*32 + ch
//   cin = (lane>>4)*8 + i
// Lane's 4 C-regs then hold (z,f) for channels c0=ocg*8+2*kq and c0+1.
// ---------------------------------------------------------------------------
__global__ __launch_bounds__(256) void prep_w_kernel(
    const float* __restrict__ w, _Float16* __restrict__ wr) {
  int idx = blockIdx.x * 256 + threadIdx.x;
  if (idx >= 55296) return;
  int i = idx & 7;
  int lane = (idx >> 3) & 63;
  int rest = idx >> 9;             // ocg*27 + tap
  int tap = rest % 27;
  int ocg = rest / 27;
  int m = lane & 15;
  int cin = (lane >> 4) * 8 + i;
  int oc = (m & 1) * 32 + ocg * 8 + (m >> 1);
  wr[idx] = (_Float16)(w[(oc * CIN_ + cin) * 27 + tap]);
}

// ---------------------------------------------------------------------------
// Kernel 1: fused Conv3d (fp16 MFMA) + gating + time recurrence.
// Grid (96,4): tile 16x6 px. Block 256 thr = 4 waves, wave = ocg (16 oc-slots
// = 8 channels x {Z,F}), all 6 rows. Weights: 27 half8 = 108 VGPR/wave.
// Ring: 4 slots x [8 rows x 18 cols][pitch 40 f16] = 46 KB -> 2 blocks/CU,
// 2 waves/SIMD. Stage loads at top of t (coalesced, lane=x), LDS writes
// after compute, one barrier/t.
// ---------------------------------------------------------------------------
#define PITCH 40
#define SROWS 8
#define SCOLS 18
#define SLICE_HF (SROWS * SCOLS * PITCH)   // 5760 f16 = 11520 B

__global__ __launch_bounds__(256, 2) void conv_rec_mfma(
    const float* __restrict__ in, const _Float16* __restrict__ wr,
    const float* __restrict__ bias, float* __restrict__ out) {
  __shared__ _Float16 in_s[4 * SLICE_HF];   // 46080 B

  const int tid = threadIdx.x;
  const int tile = blockIdx.x;   // 0..95
  const int b = blockIdx.y;      // 0..3
  const int x0 = (tile % 6) * 16;
  const int y0 = (tile / 6) * 6;
  const int lane = tid & 63;
  const int ocg = tid >> 6;      // 0..3
  const int px = lane & 15;
  const int kq = lane >> 4;      // 0..3

  // --- per-wave weights: 27 taps, gate-interleaved 16-slot frags ---
  half8 wreg[27];
  {
    const _Float16* wp = wr + (size_t)ocg * 27 * 512 + lane * 8;
#pragma unroll
    for (int tap = 0; tap < 27; ++tap)
      wreg[tap] = *(const half8*)(wp + tap * 512);
  }

  const int c0 = ocg * 8 + 2 * kq;
  f32x4 bias4;
  bias4[0] = bias[c0];          // z(c0)
  bias4[1] = bias[32 + c0];     // f(c0)
  bias4[2] = bias[c0 + 1];      // z(c0+1)
  bias4[3] = bias[32 + c0 + 1]; // f(c0+1)

  // staging thread roles
  const int s_xi = tid & 15;       // interior x lane
  const int s_q  = tid >> 4;       // rowjob sub-index (0..15)
  const int e_cin = tid & 31;      // edge role
  const int e_yy  = tid >> 5;      // 0..7
  const int e_gy  = y0 - 1 + e_yy;
  const bool e_ok = ((unsigned)e_gy < (unsigned)H_);

  // full stage (load+write), prologue use
  auto stage_full = [&](int ts) {
    _Float16* dst = in_s + (ts & 3) * SLICE_HF;
    const float* sb = in + ((size_t)(b * CIN_) * T_ + ts) * SP_;
#pragma unroll
    for (int k = 0; k < 16; ++k) {
      int rj = k * 16 + s_q;          // yy*32 + cin
      int cin = rj & 31;
      int yy = rj >> 5;
      int gy = y0 - 1 + yy;
      float v = 0.f;
      if ((unsigned)gy < (unsigned)H_)
        v = sb[(size_t)cin * (T_ * SP_) + gy * W_ + x0 + s_xi];
      dst[(yy * SCOLS + s_xi + 1) * PITCH + cin] = (_Float16)v;
    }
    float v0 = 0.f, v1 = 0.f;
    if (e_ok) {
      const float* rb = sb + (size_t)e_cin * (T_ * SP_) + e_gy * W_;
      if (x0 > 0) v0 = rb[x0 - 1];
      if (x0 + 16 < W_) v1 = rb[x0 + 16];
    }
    dst[(e_yy * SCOLS + 0) * PITCH + e_cin] = (_Float16)v0;
    dst[(e_yy * SCOLS + 17) * PITCH + e_cin] = (_Float16)v1;
  };

  // prologue: slot 3 = slice -1 = zeros; slices 0,1 -> slots 0,1
  {
    uint32_t* dz = (uint32_t*)(in_s + 3 * SLICE_HF);
    for (int e = tid; e < SLICE_HF / 2; e += 256) dz[e] = 0u;
  }
  stage_full(0);
  stage_full(1);
  __syncthreads();

  float h[6][2];
#pragma unroll
  for (int r = 0; r < 6; ++r) { h[r][0] = 0.f; h[r][1] = 0.f; }

  size_t obase = ((size_t)(b * HID_ + c0) * T_) * SP_ + y0 * W_ + x0 + px;

  for (int t = 0; t < T_; ++t) {
    const int ts = t + 2;

    // ---- phase A: issue stage loads for slice ts (held in regs) ----
    float sv[16], ev0 = 0.f, ev1 = 0.f;
    if (ts < T_) {
      const float* sb = in + ((size_t)(b * CIN_) * T_ + ts) * SP_;
#pragma unroll
      for (int k = 0; k < 16; ++k) {
        int rj = k * 16 + s_q;
        int cin = rj & 31;
        int yy = rj >> 5;
        int gy = y0 - 1 + yy;
        sv[k] = 0.f;
        if ((unsigned)gy < (unsigned)H_)
          sv[k] = sb[(size_t)cin * (T_ * SP_) + gy * W_ + x0 + s_xi];
      }
      if (e_ok) {
        const float* rb = sb + (size_t)e_cin * (T_ * SP_) + e_gy * W_;
        if (x0 > 0) ev0 = rb[x0 - 1];
        if (x0 + 16 < W_) ev1 = rb[x0 + 16];
      }
    }

    // ---- compute: 27 taps x 6 rows ----
    f32x4 acc[6];
#pragma unroll
    for (int r = 0; r < 6; ++r) acc[r] = bias4;

#pragma unroll
    for (int kd = 0; kd < 3; ++kd) {
      const _Float16* sb2 = in_s + ((t + 3 + kd) & 3) * SLICE_HF;  // slice t-1+kd
#pragma unroll
      for (int kw = 0; kw < 3; ++kw) {
        half8 brow[8];
#pragma unroll
        for (int rr = 0; rr < 8; ++rr)
          brow[rr] = *(const half8*)(sb2 + (rr * SCOLS + px + kw) * PITCH + kq * 8);
#pragma unroll
        for (int kh = 0; kh < 3; ++kh) {
          const int tap = kd * 9 + kh * 3 + kw;
#pragma unroll
          for (int r = 0; r < 6; ++r)
            acc[r] = __builtin_amdgcn_mfma_f32_16x16x32_f16(wreg[tap], brow[r + kh], acc[r], 0, 0, 0);
        }
      }
    }

    // ---- phase B: write staged slice (or zeros for ts==31) ----
    if (ts < T_) {
      _Float16* dst = in_s + (ts & 3) * SLICE_HF;
#pragma unroll
      for (int k = 0; k < 16; ++k) {
        int rj = k * 16 + s_q;
        int cin = rj & 31;
        int yy = rj >> 5;
        dst[(yy * SCOLS + s_xi + 1) * PITCH + cin] = (_Float16)sv[k];
      }
      dst[(e_yy * SCOLS + 0) * PITCH + e_cin] = (_Float16)ev0;
      dst[(e_yy * SCOLS + 17) * PITCH + e_cin] = (_Float16)ev1;
    } else if (ts == T_) {
      uint32_t* dz = (uint32_t*)(in_s + (ts & 3) * SLICE_HF);
      for (int e = tid; e < SLICE_HF / 2; e += 256) dz[e] = 0u;
    }

    // ---- gating + recurrence + store (c0 and c0+1 in-lane) ----
#pragma unroll
    for (int r = 0; r < 6; ++r) {
      float z0 = 1.f - 2.f / (1.f + __expf(2.f * acc[r][0]));
      float f0 = 1.f / (1.f + __expf(-acc[r][1]));
      h[r][0] = f0 * h[r][0] + (1.f - f0) * z0;
      out[obase + r * W_] = h[r][0];
      float z1 = 1.f - 2.f / (1.f + __expf(2.f * acc[r][2]));
      float f1 = 1.f / (1.f + __expf(-acc[r][3]));
      h[r][1] = f1 * h[r][1] + (1.f - f1) * z1;
      out[obase + (size_t)T_ * SP_ + r * W_] = h[r][1];
    }
    obase += SP_;
    __syncthreads();   // stage writes visible; ring slot safety
  }
}

// ---------------------------------------------------------------------------
// Kernel 2: per-pixel channel attention via 32x32x16 MFMA, in-place on d_out.
// PX=16 pixels/block (64B coalesced runs), 512 thr = 8 waves, 2 px/wave.
// ---------------------------------------------------------------------------
#define APIT 40

__global__ __launch_bounds__(512) void attn_mfma(
    float* __restrict__ out, const float* __restrict__ gamma) {
  __shared__ _Float16 qh_s[16][32 * APIT];   // 40960 B
  __shared__ _Float16 qt_s[16][32 * APIT];   // 40960 B
  __shared__ _Float16 at_s[8][32 * APIT];    // 20480 B

  const int tid = threadIdx.x;
  const int x0 = blockIdx.x * 16;
  const int y = blockIdx.y;
  const int b = blockIdx.z;
  const int lane = tid & 63;
  const int wv = tid >> 6;       // 0..7
  const float gm = gamma[0];

  // stage h (coalesced 64B runs), both layouts
  for (int e = tid; e < 16 * 32 * 31; e += 512) {
    int xi = e & 15;
    int q = e >> 4;
    int t = q % 31;
    int c = q / 31;
    float v = out[((size_t)(b * HID_ + c) * T_ + t) * SP_ + y * W_ + x0 + xi];
    _Float16 hv = (_Float16)v;
    qh_s[xi][c * APIT + t] = hv;
    qt_s[xi][t * APIT + c] = hv;
  }
  // zero-pad t=31 of qh (one elem per thread: 16 px x 32 c = 512)
  qh_s[tid & 15][(tid >> 4) * APIT + 31] = (_Float16)0.f;
  __syncthreads();

  const int cd = lane & 31;
  const int hi = lane >> 5;

#pragma unroll
  for (int pp = 0; pp < 2; ++pp) {
    const int px = wv * 2 + pp;

    // QK^T: S[c][d] = sum_t qh[c][t] qh[d][t]
    half8 q0 = *(const half8*)&qh_s[px][cd * APIT + hi * 8];
    half8 q1 = *(const half8*)&qh_s[px][cd * APIT + hi * 8 + 16];
    f32x16 S = {};
    S = __builtin_amdgcn_mfma_f32_32x32x16_f16(q0, q0, S, 0, 0, 0);
    S = __builtin_amdgcn_mfma_f32_32x32x16_f16(q1, q1, S, 0, 0, 0);

    // softmax over c (rows in regs + lane^32), then * 1/sqrt(32)
    float mx = S[0];
#pragma unroll
    for (int r = 1; r < 16; ++r) mx = fmaxf(mx, S[r]);
    mx = fmaxf(mx, __shfl_xor(mx, 32));
    float sm = 0.f;
    float ev[16];
#pragma unroll
    for (int r = 0; r < 16; ++r) { ev[r] = __expf(S[r] - mx); sm += ev[r]; }
    sm += __shfl_xor(sm, 32);
    const float sc = 0.17677669529663688f / sm;

#pragma unroll
    for (int r = 0; r < 16; ++r) {
      int c = (r & 3) + 8 * (r >> 2) + 4 * hi;
      at_s[wv][c * APIT + cd] = (_Float16)(ev[r] * sc);
    }

    // PV: P[c][t] = sum_d attn[c][d] qh[d][t]
    half8 a0 = *(const half8*)&at_s[wv][cd * APIT + hi * 8];
    half8 a1 = *(const half8*)&at_s[wv][cd * APIT + hi * 8 + 16];
    half8 b0 = *(const half8*)&qt_s[px][cd * APIT + hi * 8];
    half8 b1 = *(const half8*)&qt_s[px][cd * APIT + hi * 8 + 16];
    f32x16 P = {};
    P = __builtin_amdgcn_mfma_f32_32x32x16_f16(a0, b0, P, 0, 0, 0);
    P = __builtin_amdgcn_mfma_f32_32x32x16_f16(a1, b1, P, 0, 0, 0);

#pragma unroll
    for (int r = 0; r < 16; ++r) {
      int c = (r & 3) + 8 * (r >> 2) + 4 * hi;
      qt_s[px][cd * APIT + c] = (_Float16)P[r];
    }
  }
  __syncthreads();

  // store: out = gamma * ah + h (coalesced 64B runs)
  for (int e = tid; e < 16 * 32 * 31; e += 512) {
    int xi = e & 15;
    int q = e >> 4;
    int t = q % 31;
    int c = q / 31;
    float ah = (float)qt_s[xi][t * APIT + c];
    float hv = (float)qh_s[xi][c * APIT + t];
    out[((size_t)(b * HID_ + c) * T_ + t) * SP_ + y * W_ + x0 + xi] =
        gm * ah + hv;
  }
}

// ---------------------------------------------------------------------------
extern "C" void kernel_launch(void* const* d_in, const int* in_sizes, int n_in,
                              void* d_out, int out_size, void* d_ws,
                              size_t ws_size, hipStream_t stream) {
  const float* in    = (const float*)d_in[0];  // [4,32,31,96,96]
  const float* w     = (const float*)d_in[1];  // [64,32,3,3,3]
  const float* bias  = (const float*)d_in[2];  // [64]
  const float* gamma = (const float*)d_in[3];  // [1]
  float* out = (float*)d_out;                  // [4,32,31,96,96]
  _Float16* wr = (_Float16*)d_ws;              // 110 KB fp16 fragments

  prep_w_kernel<<<216, 256, 0, stream>>>(w, wr);
  conv_rec_mfma<<<dim3(96, 4), 256, 0, stream>>>(in, wr, bias, out);
  attn_mfma<<<dim3(6, 96, 4), 512, 0, stream>>>(out, gamma);
}